// Round 13
// baseline (368.550 us; speedup 1.0000x reference)
//
#include <hip/hip_runtime.h>
#include <math.h>

// DGNRNetwork: encoder MLP -> TransformerConv(32->4x32) -> mask -> TransformerConv(128->4x32) -> head
// N=50000, E=800000, B=1000, HID=32, HEADS=4, D1=128, FINAL=288
// fp16 downstream of encoder; qkv via MFMA 16x16x32_f16; attn = max-free softmax over padded
// neighbor table gathers of interleaved KV rows (256 halfs: K[0..127] | V[128..255]).
// R12 lesson: colb line-bounce (every line written by ~98 blocks across 8 non-coherent L2s)
// = 65MB of extra writeback. R13: two-pass edge build — pass A buckets edges by dst>>13 into
// contiguous buffers (coalesced int2 writes); pass B gives each 1024-node subrange ONE owner
// block (LDS slot counters, exclusive colb slice -> each line written back once; deg written
// coalesced, no memset needed).
// Graph (6 nodes): memset(bcnt) -> init[wt|passA|enc] -> mid[passB|qkv1] -> attn1 -> qkv2
//                  -> attn2 -> head

typedef _Float16 half8 __attribute__((ext_vector_type(8)));
typedef float f32x4 __attribute__((ext_vector_type(4)));

#define CAP 64          // padded neighbor-row capacity; Poisson(16): P(deg>64) ~ 1e-19
#define BSH 13          // bucket shift: range = dst >> 13 (8192 nodes/range, <=7 for N=50000)
#define BCAP 160000     // per-bucket capacity (expected ~131K for 8192-node range, 33+ sigma)
#define SSH 10          // subrange shift: 1024 nodes per pass-B owner block

__device__ inline half8 h8zero() {
    half8 r;
#pragma unroll
    for (int j = 0; j < 8; ++j) r[j] = (_Float16)0.f;
    return r;
}

// ---------------- encoder body: h0 = relu(relu(x@W1+b1)@W2+b2), fp16 out ----------------
__device__ __forceinline__ void enc_body(const float* __restrict__ x,
                                         const float* __restrict__ w1, const float* __restrict__ b1,
                                         const float* __restrict__ w2, const float* __restrict__ b2,
                                         _Float16* __restrict__ h0, int n, int bn,
                                         float* __restrict__ smem) {
    float* W1s = smem;          // 2048
    float* W2s = smem + 2048;   // 1024
    float* B1s = smem + 3072;   // 32
    float* B2s = smem + 3104;   // 32
    float* xs  = smem + 3136;   // 512
    float* hs  = smem + 3648;   // 256
    int t = threadIdx.x;
    for (int i = t; i < 64 * 32; i += 256) W1s[i] = w1[i];
    for (int i = t; i < 32 * 32; i += 256) W2s[i] = w2[i];
    if (t < 32) { B1s[t] = b1[t]; B2s[t] = b2[t]; }
    if (t < 128) {  // 8 rows x 64 floats = 128 float4, contiguous
        int row = t >> 4;
        float4 val = make_float4(0.f, 0.f, 0.f, 0.f);
        if (bn + row < n) val = *(const float4*)(x + (size_t)bn * 64 + t * 4);
        ((float4*)xs)[t] = val;
    }
    __syncthreads();
    int nn = t >> 5, c = t & 31;
    float acc = B1s[c];
#pragma unroll
    for (int i = 0; i < 64; ++i) acc += xs[nn * 64 + i] * W1s[i * 32 + c];
    acc = fmaxf(acc, 0.f);
    hs[nn * 32 + c] = acc;
    __syncthreads();
    float acc2 = B2s[c];
#pragma unroll
    for (int i = 0; i < 32; ++i) acc2 += hs[nn * 32 + i] * W2s[i * 32 + c];
    acc2 = fmaxf(acc2, 0.f);
    int node = bn + nn;
    if (node < n) h0[(size_t)node * 32 + c] = (_Float16)acc2;
}

// ---------------- kernel1: wt | passA(bucket edges) | enc fused by blockIdx range ------------
__global__ __launch_bounds__(256)
void init_kernel(const float* __restrict__ x,
                 const float* __restrict__ ew1, const float* __restrict__ eb1,
                 const float* __restrict__ ew2, const float* __restrict__ eb2,
                 _Float16* __restrict__ h0,
                 const float* __restrict__ q1, const float* __restrict__ k1,
                 const float* __restrict__ v1, _Float16* __restrict__ WT1,
                 const float* __restrict__ q2, const float* __restrict__ k2,
                 const float* __restrict__ v2, _Float16* __restrict__ WT2,
                 const int* __restrict__ srcv, const int* __restrict__ dstv,
                 int* __restrict__ bcnt, int2* __restrict__ bucket,
                 int n, int e, int wtb, int pab) {
    __shared__ float smem[3904];
    int b = blockIdx.x, t = threadIdx.x;
    if (b < wtb) {
        // WT[z*128+c][k] = Wz[k][c] (fp16), both convs back to back
        int tid = b * 256 + t;
        const int n1 = 3 * 128 * 32;
        if (tid < n1) {
            int z = tid / (128 * 32);
            int rem = tid % (128 * 32);
            int c = rem / 32, k = rem % 32;
            const float* w = (z == 0) ? q1 : ((z == 1) ? k1 : v1);
            WT1[tid] = (_Float16)w[k * 128 + c];
        } else {
            int i = tid - n1;
            if (i < 3 * 128 * 128) {
                int z = i / (128 * 128);
                int rem = i % (128 * 128);
                int c = rem / 128, k = rem % 128;
                const float* w = (z == 0) ? q2 : ((z == 1) ? k2 : v2);
                WT2[i] = (_Float16)w[k * 128 + c];
            }
        }
    } else if (b < wtb + pab) {
        // pass A: bucket 1024 edges/block by dst>>BSH; per-block LDS count -> one global
        // atomicAdd per range -> placement via LDS cursors. Coalesced int2 writes.
        int* scnt  = (int*)smem;        // 8
        int* sbase = scnt + 8;          // 8
        int* scur  = scnt + 16;         // 8
        if (t < 8) scnt[t] = 0;
        __syncthreads();
        int base = (b - wtb) * 1024 + t * 4;
        int ds[4], ss[4], rs[4];
        int nv = 0;
        if (base + 3 < e) {
            int4 dv = *(const int4*)(dstv + base);
            int4 sv = *(const int4*)(srcv + base);
            ds[0] = dv.x; ds[1] = dv.y; ds[2] = dv.z; ds[3] = dv.w;
            ss[0] = sv.x; ss[1] = sv.y; ss[2] = sv.z; ss[3] = sv.w;
            nv = 4;
        } else {
            for (int j = 0; j < 4; ++j)
                if (base + j < e) { ds[nv] = dstv[base + j]; ss[nv] = srcv[base + j]; ++nv; }
        }
        for (int j = 0; j < nv; ++j) { rs[j] = ds[j] >> BSH; atomicAdd(&scnt[rs[j]], 1); }
        __syncthreads();
        if (t < 8) { sbase[t] = scnt[t] ? atomicAdd(&bcnt[t], scnt[t]) : 0; scur[t] = 0; }
        __syncthreads();
        for (int j = 0; j < nv; ++j) {
            int pos = sbase[rs[j]] + atomicAdd(&scur[rs[j]], 1);
            if (pos < BCAP) bucket[(size_t)rs[j] * BCAP + pos] = make_int2(ss[j], ds[j]);
        }
    } else {
        enc_body(x, ew1, eb1, ew2, eb2, h0, n, (b - wtb - pab) * 8, smem);
    }
}

// ---------------- qkv GEMM body via MFMA: Y_z[n x 128] = (X .* mask?) @ Wz + bz -------------
// 256 thr = 4 waves (2x2): wr -> 32 rows, wc -> 64 cols. BM=64, K-tile=32.
// A-frag: lane row=l&15, k=(l>>4)*8+j ; B-frag: lane col=l&15, same k ; C/D: col=l&15, row=(l>>4)*4+reg.
__device__ __forceinline__ void qkv_body(const _Float16* __restrict__ X, const float* __restrict__ mask,
                                         const _Float16* __restrict__ WT,
                                         const float* __restrict__ Bq, const float* __restrict__ Bk,
                                         const float* __restrict__ Bv,
                                         _Float16* __restrict__ Q, _Float16* __restrict__ KV,
                                         int n, int IN, int bx, int z,
                                         _Float16* __restrict__ Xs, _Float16* __restrict__ Ws) {
    int t = threadIdx.x;
    int bm = bx * 64;
    const float* Bz = (z == 0) ? Bq : ((z == 1) ? Bk : Bv);
    _Float16* Y;
    size_t ystride;
    if (z == 0) { Y = Q; ystride = 128; }
    else        { Y = KV + (z == 1 ? 0 : 128); ystride = 256; }

    int lane = t & 63, w = t >> 6;
    int wr = w >> 1, wc = w & 1;
    int fr = lane & 15, k0 = (lane >> 4) * 8;
    f32x4 acc[2][4];
#pragma unroll
    for (int i = 0; i < 2; ++i)
#pragma unroll
        for (int j = 0; j < 4; ++j)
#pragma unroll
            for (int r = 0; r < 4; ++r) acc[i][j][r] = 0.f;

    // staging roles: X -> row t>>2 (0..63), seg (t&3)*8 ; W -> rows t>>2 and 64+(t>>2)
    int srow = t >> 2, sseg = (t & 3) * 8;
    int snode = bm + srow;
    const _Float16* xbase = X + (size_t)snode * IN + sseg;
    const _Float16* wbase = WT + (size_t)(z * 128) * IN + sseg;
    bool xvalid = (snode < n);
    if (xvalid && mask) xvalid = (mask[snode] != 0.f);   // mask is exactly 0/1

    for (int kt = 0; kt < IN; kt += 32) {
        half8 xv = h8zero();
        if (xvalid) xv = *(const half8*)(xbase + kt);
        half8 wv0 = *(const half8*)(wbase + (size_t)srow * IN + kt);
        half8 wv1 = *(const half8*)(wbase + (size_t)(64 + srow) * IN + kt);
        __syncthreads();   // protect LDS reuse from previous iteration
        *(half8*)&Xs[srow * 40 + sseg] = xv;
        *(half8*)&Ws[srow * 40 + sseg] = wv0;
        *(half8*)&Ws[(64 + srow) * 40 + sseg] = wv1;
        __syncthreads();
        half8 a0 = *(const half8*)&Xs[(wr * 32 + fr) * 40 + k0];
        half8 a1 = *(const half8*)&Xs[(wr * 32 + 16 + fr) * 40 + k0];
#pragma unroll
        for (int tc = 0; tc < 4; ++tc) {
            half8 bfr = *(const half8*)&Ws[(wc * 64 + tc * 16 + fr) * 40 + k0];
            acc[0][tc] = __builtin_amdgcn_mfma_f32_16x16x32_f16(a0, bfr, acc[0][tc], 0, 0, 0);
            acc[1][tc] = __builtin_amdgcn_mfma_f32_16x16x32_f16(a1, bfr, acc[1][tc], 0, 0, 0);
        }
    }
#pragma unroll
    for (int tc = 0; tc < 4; ++tc) {
        int colc = wc * 64 + tc * 16 + fr;
        float bias = Bz[colc];
#pragma unroll
        for (int tr = 0; tr < 2; ++tr) {
#pragma unroll
            for (int reg = 0; reg < 4; ++reg) {
                int node = bm + wr * 32 + tr * 16 + (lane >> 4) * 4 + reg;
                if (node < n) Y[(size_t)node * ystride + colc] = (_Float16)(acc[tr][tc][reg] + bias);
            }
        }
    }
}

// ---------------- kernel2: passB(build colb, exclusive owners) | qkv1 ----------------
__global__ __launch_bounds__(256)
void mid_kernel(const int* __restrict__ bcnt, const int2* __restrict__ bucket,
                int* __restrict__ deg, int* __restrict__ colb,
                const _Float16* __restrict__ h0, const _Float16* __restrict__ WT1,
                const float* __restrict__ bq, const float* __restrict__ bk,
                const float* __restrict__ bv,
                _Float16* __restrict__ Q, _Float16* __restrict__ KV,
                int n, int pbb, int nqx) {
    __shared__ _Float16 sm[64 * 40 + 128 * 40];   // 15360 B; passB uses first 4KB as int
    int b = blockIdx.x, t = threadIdx.x;
    if (b < pbb) {
        // owner block for nodes [b<<SSH, b<<SSH + 1024): LDS slot counters, exclusive colb slice
        int lo = b << SSH;
        int hi = lo + (1 << SSH); if (hi > n) hi = n;
        int r = b >> (BSH - SSH);
        int* ldeg = (int*)sm;
        for (int i = t; i < (1 << SSH); i += 256) ldeg[i] = 0;
        __syncthreads();
        int cnt = bcnt[r]; if (cnt > BCAP) cnt = BCAP;
        for (int i = t; i < cnt; i += 256) {
            int2 ed = bucket[(size_t)r * BCAP + i];
            int d = ed.y;
            if (d >= lo && d < hi) {
                int slot = atomicAdd(&ldeg[d - lo], 1);
                if (slot < CAP) colb[d * CAP + slot] = ed.x;
            }
        }
        __syncthreads();
        for (int i = t; i < hi - lo; i += 256) deg[lo + i] = ldeg[i];
    } else {
        int rr = b - pbb;
        qkv_body(h0, nullptr, WT1, bq, bk, bv, Q, KV, n, 32, rr % nqx, rr / nqx,
                 sm, sm + 64 * 40);
    }
}

__global__ __launch_bounds__(256)
void qkv_kernel(const _Float16* __restrict__ X, const float* __restrict__ mask,
                const _Float16* __restrict__ WT,
                const float* __restrict__ Bq, const float* __restrict__ Bk,
                const float* __restrict__ Bv,
                _Float16* __restrict__ Q, _Float16* __restrict__ KV, int n, int IN) {
    __shared__ _Float16 Xs[64 * 40];
    __shared__ _Float16 Ws[128 * 40];
    qkv_body(X, mask, WT, Bq, Bk, Bv, Q, KV, n, IN, blockIdx.x, blockIdx.y, Xs, Ws);
}

// ---------------- attention: one wave per dst node, 4 edge slots, MAX-FREE softmax ----------
// softmax is shift-invariant; logits here are O(1) so exp2 with +/-120 clamp is exact enough.
// lane: es=lane>>4 (4 edge slots); l=lane&15 -> 8 dims at d0=l*8; head = l>>2
__global__ __launch_bounds__(256)
void attn_kernel(const _Float16* __restrict__ q, const _Float16* __restrict__ kv,
                 const int* __restrict__ deg, const int* __restrict__ col,
                 _Float16* __restrict__ out, int n) {
    int w = threadIdx.x >> 6;
    int lane = threadIdx.x & 63;
    int node = blockIdx.x * 4 + w;
    if (node >= n) return;
    int es = lane >> 4;
    int l = lane & 15;
    int d0 = l * 8;
    float qf[8];
    {
        half8 qh = *(const half8*)(q + (size_t)node * 128 + d0);
#pragma unroll
        for (int j = 0; j < 8; ++j) qf[j] = (float)qh[j];
    }
    int start = node * CAP;
    int len = deg[node];
    len = (len > CAP) ? CAP : len;
    float s = 0.f;
    float acc[8];
#pragma unroll
    for (int j = 0; j < 8; ++j) acc[j] = 0.f;
    const float sc = 0.17677669529663689f * 1.4426950408889634f;  // 1/sqrt(32) * log2(e)

    for (int i = es; i < len; i += 4) {
        int srcn = col[start + i];
        const _Float16* row = kv + (size_t)srcn * 256 + d0;
        half8 kf = *(const half8*)row;
        float dot = 0.f;
#pragma unroll
        for (int j = 0; j < 8; ++j) dot += qf[j] * (float)kf[j];
        dot += __shfl_xor(dot, 1);
        dot += __shfl_xor(dot, 2);            // sum over the 4 lanes of this head
        float a = fminf(fmaxf(dot * sc, -120.f), 120.f);
        float p = __builtin_amdgcn_exp2f(a);
        half8 vf = *(const half8*)(row + 128);
        s += p;
#pragma unroll
        for (int j = 0; j < 8; ++j) acc[j] += p * (float)vf[j];
    }
    // merge the four edge slots (pure sums — no max bookkeeping)
#pragma unroll
    for (int half = 16; half <= 32; half <<= 1) {
        s += __shfl_xor(s, half);
#pragma unroll
        for (int j = 0; j < 8; ++j) acc[j] += __shfl_xor(acc[j], half);
    }
    if (es == 0) {
        float inv = 1.f / (s + 1e-16f);
        half8 r;
#pragma unroll
        for (int j = 0; j < 8; ++j) r[j] = (_Float16)fmaxf(acc[j] * inv, 0.f);
        *(half8*)(out + (size_t)node * 128 + d0) = r;
    }
}

// ---------------- output head: concat(x1,x2,x3) @ out_w + out_b ----------------
__global__ void head_kernel(const _Float16* __restrict__ h0, const _Float16* __restrict__ h1,
                            const _Float16* __restrict__ h2, const int* __restrict__ gi,
                            const float* __restrict__ ow, const float* __restrict__ ob,
                            float* __restrict__ out, int bsz) {
    int idx = blockIdx.x * 256 + threadIdx.x;
    if (idx >= bsz * 5) return;
    int b = idx / 5, c = idx % 5;
    int g = gi[b];
    float acc = ob[c];
    const _Float16* r0 = h0 + (size_t)g * 32;
#pragma unroll
    for (int i = 0; i < 32; ++i) acc += (float)r0[i] * ow[i * 5 + c];
    const _Float16* r1 = h1 + (size_t)g * 128;
#pragma unroll
    for (int i = 0; i < 128; ++i) acc += (float)r1[i] * ow[(32 + i) * 5 + c];
    const _Float16* r2 = h2 + (size_t)g * 128;
#pragma unroll
    for (int i = 0; i < 128; ++i) acc += (float)r2[i] * ow[(160 + i) * 5 + c];
    out[idx] = acc;
}

extern "C" void kernel_launch(void* const* d_in, const int* in_sizes, int n_in,
                              void* d_out, int out_size, void* d_ws, size_t ws_size,
                              hipStream_t stream) {
    const float* x    = (const float*)d_in[0];
    const int*   ei   = (const int*)d_in[1];
    const float* dm   = (const float*)d_in[2];
    const int*   gi   = (const int*)d_in[3];
    const float* ew1  = (const float*)d_in[4];
    const float* eb1  = (const float*)d_in[5];
    const float* ew2  = (const float*)d_in[6];
    const float* eb2  = (const float*)d_in[7];
    const float* c1wq = (const float*)d_in[8];
    const float* c1bq = (const float*)d_in[9];
    const float* c1wk = (const float*)d_in[10];
    const float* c1bk = (const float*)d_in[11];
    const float* c1wv = (const float*)d_in[12];
    const float* c1bv = (const float*)d_in[13];
    const float* c2wq = (const float*)d_in[14];
    const float* c2bq = (const float*)d_in[15];
    const float* c2wk = (const float*)d_in[16];
    const float* c2bk = (const float*)d_in[17];
    const float* c2wv = (const float*)d_in[18];
    const float* c2bv = (const float*)d_in[19];
    const float* ow   = (const float*)d_in[20];
    const float* ob   = (const float*)d_in[21];
    float* out = (float*)d_out;

    int N = in_sizes[0] / 64;
    int E = in_sizes[1] / 2;
    int B = in_sizes[3];
    const int* srcv = ei;
    const int* dstv = ei + E;

    // workspace carve-up
    char* ws = (char*)d_ws;
    size_t off = 0;
    auto alloc = [&](size_t bytes) -> void* {
        void* p = ws + off;
        off += (bytes + 255) & ~(size_t)255;
        return p;
    };
    _Float16* h0   = (_Float16*)alloc((size_t)N * 32 * 2);
    _Float16* h1   = (_Float16*)alloc((size_t)N * 128 * 2);
    _Float16* h2   = (_Float16*)alloc((size_t)N * 128 * 2);
    _Float16* Q    = (_Float16*)alloc((size_t)N * 128 * 2);
    _Float16* KV   = (_Float16*)alloc((size_t)N * 256 * 2);
    _Float16* WT1  = (_Float16*)alloc((size_t)3 * 128 * 32 * 2);
    _Float16* WT2  = (_Float16*)alloc((size_t)3 * 128 * 128 * 2);
    int*  bcnt   = (int*)alloc(256);
    int*  deg    = (int*)alloc((size_t)N * 4);
    int*  colb   = (int*)alloc((size_t)N * CAP * 4);
    int2* bucket = (int2*)alloc((size_t)8 * BCAP * 8);

    hipMemsetAsync(bcnt, 0, 256, stream);   // bucket counters only; deg written by passB

    int pab  = (E + 1023) / 1024;                  // 782 (pass A, 4 edges/thread)
    int encb = (N + 7) / 8;                        // 6250
    int pbb  = (N + (1 << SSH) - 1) >> SSH;        // 49 (pass B owner blocks)
    int nqx  = (N + 63) / 64;                      // 782
    int wtb  = (3 * 128 * 32 + 3 * 128 * 128 + 255) / 256;   // 240

    // kernel1: wt | passA | enc
    init_kernel<<<wtb + pab + encb, 256, 0, stream>>>(
        x, ew1, eb1, ew2, eb2, h0,
        c1wq, c1wk, c1wv, WT1, c2wq, c2wk, c2wv, WT2,
        srcv, dstv, bcnt, bucket, N, E, wtb, pab);

    // kernel2: passB | qkv1 (colb build overlaps the conv1 GEMM)
    mid_kernel<<<pbb + 3 * nqx, 256, 0, stream>>>(
        bcnt, bucket, deg, colb, h0, WT1, c1bq, c1bk, c1bv, Q, KV, N, pbb, nqx);

    attn_kernel<<<(N + 3) / 4, 256, 0, stream>>>(Q, KV, deg, colb, h1, N);

    dim3 gq(nqx, 3);
    // conv2: IN=128, input = h1 * dm_mask (mask fused into staging; x2 gathers unmasked h1)
    qkv_kernel<<<gq, 256, 0, stream>>>(h1, dm, WT2, c2bq, c2bk, c2bv, Q, KV, N, 128);
    attn_kernel<<<(N + 3) / 4, 256, 0, stream>>>(Q, KV, deg, colb, h2, N);

    head_kernel<<<(B * 5 + 255) / 256, 256, 0, stream>>>(h0, h1, h2, gi, ow, ob, out, B);
}

// Round 14
// 216.039 us; speedup vs baseline: 1.7059x; 1.7059x over previous
//
#include <hip/hip_runtime.h>
#include <math.h>

// DGNRNetwork: encoder MLP -> TransformerConv(32->4x32) -> mask -> TransformerConv(128->4x32) -> head
// N=50000, E=800000, B=1000, HID=32, HEADS=4, D1=128, FINAL=288
// fp16 downstream of encoder; qkv via MFMA 16x16x32_f16; attn = max-free softmax over padded
// neighbor table gathers of interleaved KV rows (256 halfs: K[0..127] | V[128..255]).
// CHAMPION (R12 structure, 217.3us). R13's two-pass exclusive-owner build regressed (49 owner
// blocks scanning 114K-edge buckets = latency-bound at 6% occupancy); reverted.
// Budget at this structure's floor: attn 2x56.5us (gather-locality floor: FETCH 181MB ~= per-XCD
// KV fetch minimum @3.5TB/s; lower-VALU variant measured slower), mid 58us (edge scatter overlapped
// with qkv1; write-amplification attacked twice, both neutral-or-worse), init ~20, qkv2 ~24, head ~2.
// Graph (6 nodes): memset(deg) -> init[zero|wt|enc] -> mid[edges|qkv1] -> attn1 -> qkv2 -> attn2 -> head

typedef _Float16 half8 __attribute__((ext_vector_type(8)));
typedef float f32x4 __attribute__((ext_vector_type(4)));

#define CAP 64      // padded neighbor-row capacity; Poisson(16): P(deg>64) ~ 1e-19 per node
#define ECHUNK 8192 // edges per chunk (each chunk scanned by 8 blocks, one per dst range)

__device__ inline half8 h8zero() {
    half8 r;
#pragma unroll
    for (int j = 0; j < 8; ++j) r[j] = (_Float16)0.f;
    return r;
}

// ---------------- encoder body: h0 = relu(relu(x@W1+b1)@W2+b2), fp16 out ----------------
__device__ __forceinline__ void enc_body(const float* __restrict__ x,
                                         const float* __restrict__ w1, const float* __restrict__ b1,
                                         const float* __restrict__ w2, const float* __restrict__ b2,
                                         _Float16* __restrict__ h0, int n, int bn,
                                         float* __restrict__ smem) {
    float* W1s = smem;          // 2048
    float* W2s = smem + 2048;   // 1024
    float* B1s = smem + 3072;   // 32
    float* B2s = smem + 3104;   // 32
    float* xs  = smem + 3136;   // 512
    float* hs  = smem + 3648;   // 256
    int t = threadIdx.x;
    for (int i = t; i < 64 * 32; i += 256) W1s[i] = w1[i];
    for (int i = t; i < 32 * 32; i += 256) W2s[i] = w2[i];
    if (t < 32) { B1s[t] = b1[t]; B2s[t] = b2[t]; }
    if (t < 128) {  // 8 rows x 64 floats = 128 float4, contiguous
        int row = t >> 4;
        float4 val = make_float4(0.f, 0.f, 0.f, 0.f);
        if (bn + row < n) val = *(const float4*)(x + (size_t)bn * 64 + t * 4);
        ((float4*)xs)[t] = val;
    }
    __syncthreads();
    int nn = t >> 5, c = t & 31;
    float acc = B1s[c];
#pragma unroll
    for (int i = 0; i < 64; ++i) acc += xs[nn * 64 + i] * W1s[i * 32 + c];
    acc = fmaxf(acc, 0.f);
    hs[nn * 32 + c] = acc;
    __syncthreads();
    float acc2 = B2s[c];
#pragma unroll
    for (int i = 0; i < 32; ++i) acc2 += hs[nn * 32 + i] * W2s[i * 32 + c];
    acc2 = fmaxf(acc2, 0.f);
    int node = bn + nn;
    if (node < n) h0[(size_t)node * 32 + c] = (_Float16)acc2;
}

// ---------------- kernel1: zero(deg) | wt | enc fused by blockIdx range ----------------
__global__ __launch_bounds__(256)
void init_kernel(const float* __restrict__ x,
                 const float* __restrict__ ew1, const float* __restrict__ eb1,
                 const float* __restrict__ ew2, const float* __restrict__ eb2,
                 _Float16* __restrict__ h0,
                 const float* __restrict__ q1, const float* __restrict__ k1,
                 const float* __restrict__ v1, _Float16* __restrict__ WT1,
                 const float* __restrict__ q2, const float* __restrict__ k2,
                 const float* __restrict__ v2, _Float16* __restrict__ WT2,
                 int* __restrict__ deg,
                 int n, int zb, int wtb) {
    __shared__ float smem[3904];
    int b = blockIdx.x, t = threadIdx.x;
    if (b < zb) {
        int i = b * 256 + t;
        if (i < n) deg[i] = 0;
    } else if (b < zb + wtb) {
        // WT[z*128+c][k] = Wz[k][c] (fp16), both convs back to back
        int tid = (b - zb) * 256 + t;
        const int n1 = 3 * 128 * 32;
        if (tid < n1) {
            int z = tid / (128 * 32);
            int rem = tid % (128 * 32);
            int c = rem / 32, k = rem % 32;
            const float* w = (z == 0) ? q1 : ((z == 1) ? k1 : v1);
            WT1[tid] = (_Float16)w[k * 128 + c];
        } else {
            int i = tid - n1;
            if (i < 3 * 128 * 128) {
                int z = i / (128 * 128);
                int rem = i % (128 * 128);
                int c = rem / 128, k = rem % 128;
                const float* w = (z == 0) ? q2 : ((z == 1) ? k2 : v2);
                WT2[i] = (_Float16)w[k * 128 + c];
            }
        }
    } else {
        enc_body(x, ew1, eb1, ew2, eb2, h0, n, (b - zb - wtb) * 8, smem);
    }
}

// ---------------- qkv GEMM body via MFMA: Y_z[n x 128] = (X .* mask?) @ Wz + bz -------------
// 256 thr = 4 waves (2x2): wr -> 32 rows, wc -> 64 cols. BM=64, K-tile=32.
// A-frag: lane row=l&15, k=(l>>4)*8+j ; B-frag: lane col=l&15, same k ; C/D: col=l&15, row=(l>>4)*4+reg.
__device__ __forceinline__ void qkv_body(const _Float16* __restrict__ X, const float* __restrict__ mask,
                                         const _Float16* __restrict__ WT,
                                         const float* __restrict__ Bq, const float* __restrict__ Bk,
                                         const float* __restrict__ Bv,
                                         _Float16* __restrict__ Q, _Float16* __restrict__ KV,
                                         int n, int IN, int bx, int z,
                                         _Float16* __restrict__ Xs, _Float16* __restrict__ Ws) {
    int t = threadIdx.x;
    int bm = bx * 64;
    const float* Bz = (z == 0) ? Bq : ((z == 1) ? Bk : Bv);
    _Float16* Y;
    size_t ystride;
    if (z == 0) { Y = Q; ystride = 128; }
    else        { Y = KV + (z == 1 ? 0 : 128); ystride = 256; }

    int lane = t & 63, w = t >> 6;
    int wr = w >> 1, wc = w & 1;
    int fr = lane & 15, k0 = (lane >> 4) * 8;
    f32x4 acc[2][4];
#pragma unroll
    for (int i = 0; i < 2; ++i)
#pragma unroll
        for (int j = 0; j < 4; ++j)
#pragma unroll
            for (int r = 0; r < 4; ++r) acc[i][j][r] = 0.f;

    // staging roles: X -> row t>>2 (0..63), seg (t&3)*8 ; W -> rows t>>2 and 64+(t>>2)
    int srow = t >> 2, sseg = (t & 3) * 8;
    int snode = bm + srow;
    const _Float16* xbase = X + (size_t)snode * IN + sseg;
    const _Float16* wbase = WT + (size_t)(z * 128) * IN + sseg;
    bool xvalid = (snode < n);
    if (xvalid && mask) xvalid = (mask[snode] != 0.f);   // mask is exactly 0/1

    for (int kt = 0; kt < IN; kt += 32) {
        half8 xv = h8zero();
        if (xvalid) xv = *(const half8*)(xbase + kt);
        half8 wv0 = *(const half8*)(wbase + (size_t)srow * IN + kt);
        half8 wv1 = *(const half8*)(wbase + (size_t)(64 + srow) * IN + kt);
        __syncthreads();   // protect LDS reuse from previous iteration
        *(half8*)&Xs[srow * 40 + sseg] = xv;
        *(half8*)&Ws[srow * 40 + sseg] = wv0;
        *(half8*)&Ws[(64 + srow) * 40 + sseg] = wv1;
        __syncthreads();
        half8 a0 = *(const half8*)&Xs[(wr * 32 + fr) * 40 + k0];
        half8 a1 = *(const half8*)&Xs[(wr * 32 + 16 + fr) * 40 + k0];
#pragma unroll
        for (int tc = 0; tc < 4; ++tc) {
            half8 bfr = *(const half8*)&Ws[(wc * 64 + tc * 16 + fr) * 40 + k0];
            acc[0][tc] = __builtin_amdgcn_mfma_f32_16x16x32_f16(a0, bfr, acc[0][tc], 0, 0, 0);
            acc[1][tc] = __builtin_amdgcn_mfma_f32_16x16x32_f16(a1, bfr, acc[1][tc], 0, 0, 0);
        }
    }
#pragma unroll
    for (int tc = 0; tc < 4; ++tc) {
        int colc = wc * 64 + tc * 16 + fr;
        float bias = Bz[colc];
#pragma unroll
        for (int tr = 0; tr < 2; ++tr) {
#pragma unroll
            for (int reg = 0; reg < 4; ++reg) {
                int node = bm + wr * 32 + tr * 16 + (lane >> 4) * 4 + reg;
                if (node < n) Y[(size_t)node * ystride + colc] = (_Float16)(acc[tr][tc][reg] + bias);
            }
        }
    }
}

// ---------------- kernel2: edges(dst-partitioned) | qkv1 fused by blockIdx range ----------------
__global__ __launch_bounds__(256)
void mid_kernel(const int* __restrict__ srcv, const int* __restrict__ dstv,
                int* __restrict__ deg, int* __restrict__ colb,
                const _Float16* __restrict__ h0, const _Float16* __restrict__ WT1,
                const float* __restrict__ bq, const float* __restrict__ bk,
                const float* __restrict__ bv,
                _Float16* __restrict__ Q, _Float16* __restrict__ KV,
                int n, int e, int edgeb, int nqx) {
    __shared__ _Float16 sm[64 * 40 + 128 * 40];
    int b = blockIdx.x, t = threadIdx.x;
    if (b < edgeb) {
        // 8 blocks per chunk: block keeps only dst in its range -> writes confined to a
        // small colb slice (one L2, write-back once instead of per-edge line thrash)
        int g  = b & 7;
        int ci = b >> 3;
        int npg = (n + 7) / 8;
        int lo = g * npg;
        int hi = lo + npg; if (hi > n) hi = n;
        int e0 = ci * ECHUNK;
        int e1 = e0 + ECHUNK; if (e1 > e) e1 = e;
        for (int i = e0 + t * 4; i < e1; i += 1024) {
            if (i + 3 < e1) {
                int4 dv = *(const int4*)(dstv + i);
                int4 sv = *(const int4*)(srcv + i);
#pragma unroll
                for (int j = 0; j < 4; ++j) {
                    int d = (&dv.x)[j];
                    if (d >= lo && d < hi) {
                        int slot = atomicAdd(&deg[d], 1);
                        if (slot < CAP) colb[d * CAP + slot] = (&sv.x)[j];
                    }
                }
            } else {
                for (int i2 = i; i2 < e1; ++i2) {
                    int d = dstv[i2];
                    if (d >= lo && d < hi) {
                        int slot = atomicAdd(&deg[d], 1);
                        if (slot < CAP) colb[d * CAP + slot] = srcv[i2];
                    }
                }
            }
        }
    } else {
        int r = b - edgeb;
        qkv_body(h0, nullptr, WT1, bq, bk, bv, Q, KV, n, 32, r % nqx, r / nqx,
                 sm, sm + 64 * 40);
    }
}

__global__ __launch_bounds__(256)
void qkv_kernel(const _Float16* __restrict__ X, const float* __restrict__ mask,
                const _Float16* __restrict__ WT,
                const float* __restrict__ Bq, const float* __restrict__ Bk,
                const float* __restrict__ Bv,
                _Float16* __restrict__ Q, _Float16* __restrict__ KV, int n, int IN) {
    __shared__ _Float16 Xs[64 * 40];
    __shared__ _Float16 Ws[128 * 40];
    qkv_body(X, mask, WT, Bq, Bk, Bv, Q, KV, n, IN, blockIdx.x, blockIdx.y, Xs, Ws);
}

// ---------------- attention: one wave per dst node, 4 edge slots, MAX-FREE softmax ----------
// softmax is shift-invariant; logits here are O(1) so exp2 with +/-120 clamp is exact enough.
// lane: es=lane>>4 (4 edge slots); l=lane&15 -> 8 dims at d0=l*8; head = l>>2
__global__ __launch_bounds__(256)
void attn_kernel(const _Float16* __restrict__ q, const _Float16* __restrict__ kv,
                 const int* __restrict__ deg, const int* __restrict__ col,
                 _Float16* __restrict__ out, int n) {
    int w = threadIdx.x >> 6;
    int lane = threadIdx.x & 63;
    int node = blockIdx.x * 4 + w;
    if (node >= n) return;
    int es = lane >> 4;
    int l = lane & 15;
    int d0 = l * 8;
    float qf[8];
    {
        half8 qh = *(const half8*)(q + (size_t)node * 128 + d0);
#pragma unroll
        for (int j = 0; j < 8; ++j) qf[j] = (float)qh[j];
    }
    int start = node * CAP;
    int len = deg[node];
    len = (len > CAP) ? CAP : len;
    float s = 0.f;
    float acc[8];
#pragma unroll
    for (int j = 0; j < 8; ++j) acc[j] = 0.f;
    const float sc = 0.17677669529663689f * 1.4426950408889634f;  // 1/sqrt(32) * log2(e)

    for (int i = es; i < len; i += 4) {
        int srcn = col[start + i];
        const _Float16* row = kv + (size_t)srcn * 256 + d0;
        half8 kf = *(const half8*)row;
        float dot = 0.f;
#pragma unroll
        for (int j = 0; j < 8; ++j) dot += qf[j] * (float)kf[j];
        dot += __shfl_xor(dot, 1);
        dot += __shfl_xor(dot, 2);            // sum over the 4 lanes of this head
        float a = fminf(fmaxf(dot * sc, -120.f), 120.f);
        float p = __builtin_amdgcn_exp2f(a);
        half8 vf = *(const half8*)(row + 128);
        s += p;
#pragma unroll
        for (int j = 0; j < 8; ++j) acc[j] += p * (float)vf[j];
    }
    // merge the four edge slots (pure sums — no max bookkeeping)
#pragma unroll
    for (int half = 16; half <= 32; half <<= 1) {
        s += __shfl_xor(s, half);
#pragma unroll
        for (int j = 0; j < 8; ++j) acc[j] += __shfl_xor(acc[j], half);
    }
    if (es == 0) {
        float inv = 1.f / (s + 1e-16f);
        half8 r;
#pragma unroll
        for (int j = 0; j < 8; ++j) r[j] = (_Float16)fmaxf(acc[j] * inv, 0.f);
        *(half8*)(out + (size_t)node * 128 + d0) = r;
    }
}

// ---------------- output head: concat(x1,x2,x3) @ out_w + out_b ----------------
__global__ void head_kernel(const _Float16* __restrict__ h0, const _Float16* __restrict__ h1,
                            const _Float16* __restrict__ h2, const int* __restrict__ gi,
                            const float* __restrict__ ow, const float* __restrict__ ob,
                            float* __restrict__ out, int bsz) {
    int idx = blockIdx.x * 256 + threadIdx.x;
    if (idx >= bsz * 5) return;
    int b = idx / 5, c = idx % 5;
    int g = gi[b];
    float acc = ob[c];
    const _Float16* r0 = h0 + (size_t)g * 32;
#pragma unroll
    for (int i = 0; i < 32; ++i) acc += (float)r0[i] * ow[i * 5 + c];
    const _Float16* r1 = h1 + (size_t)g * 128;
#pragma unroll
    for (int i = 0; i < 128; ++i) acc += (float)r1[i] * ow[(32 + i) * 5 + c];
    const _Float16* r2 = h2 + (size_t)g * 128;
#pragma unroll
    for (int i = 0; i < 128; ++i) acc += (float)r2[i] * ow[(160 + i) * 5 + c];
    out[idx] = acc;
}

extern "C" void kernel_launch(void* const* d_in, const int* in_sizes, int n_in,
                              void* d_out, int out_size, void* d_ws, size_t ws_size,
                              hipStream_t stream) {
    const float* x    = (const float*)d_in[0];
    const int*   ei   = (const int*)d_in[1];
    const float* dm   = (const float*)d_in[2];
    const int*   gi   = (const int*)d_in[3];
    const float* ew1  = (const float*)d_in[4];
    const float* eb1  = (const float*)d_in[5];
    const float* ew2  = (const float*)d_in[6];
    const float* eb2  = (const float*)d_in[7];
    const float* c1wq = (const float*)d_in[8];
    const float* c1bq = (const float*)d_in[9];
    const float* c1wk = (const float*)d_in[10];
    const float* c1bk = (const float*)d_in[11];
    const float* c1wv = (const float*)d_in[12];
    const float* c1bv = (const float*)d_in[13];
    const float* c2wq = (const float*)d_in[14];
    const float* c2bq = (const float*)d_in[15];
    const float* c2wk = (const float*)d_in[16];
    const float* c2bk = (const float*)d_in[17];
    const float* c2wv = (const float*)d_in[18];
    const float* c2bv = (const float*)d_in[19];
    const float* ow   = (const float*)d_in[20];
    const float* ob   = (const float*)d_in[21];
    float* out = (float*)d_out;

    int N = in_sizes[0] / 64;
    int E = in_sizes[1] / 2;
    int B = in_sizes[3];
    const int* srcv = ei;
    const int* dstv = ei + E;

    // workspace carve-up
    char* ws = (char*)d_ws;
    size_t off = 0;
    auto alloc = [&](size_t bytes) -> void* {
        void* p = ws + off;
        off += (bytes + 255) & ~(size_t)255;
        return p;
    };
    _Float16* h0   = (_Float16*)alloc((size_t)N * 32 * 2);
    _Float16* h1   = (_Float16*)alloc((size_t)N * 128 * 2);
    _Float16* h2   = (_Float16*)alloc((size_t)N * 128 * 2);
    _Float16* Q    = (_Float16*)alloc((size_t)N * 128 * 2);
    _Float16* KV   = (_Float16*)alloc((size_t)N * 256 * 2);
    _Float16* WT1  = (_Float16*)alloc((size_t)3 * 128 * 32 * 2);
    _Float16* WT2  = (_Float16*)alloc((size_t)3 * 128 * 128 * 2);
    int* deg   = (int*)alloc((size_t)N * 4);
    int* colb  = (int*)alloc((size_t)N * CAP * 4);

    int zb    = (N + 255) / 256;                   // 196 (deg zeroing)
    int edgeb = ((E + ECHUNK - 1) / ECHUNK) * 8;   // 98*8 = 784
    int encb  = (N + 7) / 8;                       // 6250
    int nqx   = (N + 63) / 64;                     // 782
    int wtb   = (3 * 128 * 32 + 3 * 128 * 128 + 255) / 256;   // 240

    // kernel1: zero(deg) | wt | enc
    init_kernel<<<zb + wtb + encb, 256, 0, stream>>>(
        x, ew1, eb1, ew2, eb2, h0,
        c1wq, c1wk, c1wv, WT1, c2wq, c2wk, c2wv, WT2,
        deg, N, zb, wtb);

    // kernel2: edges | qkv1 (edge build overlaps the conv1 GEMM)
    mid_kernel<<<edgeb + 3 * nqx, 256, 0, stream>>>(
        srcv, dstv, deg, colb, h0, WT1, c1bq, c1bk, c1bv, Q, KV, N, E, edgeb, nqx);

    attn_kernel<<<(N + 3) / 4, 256, 0, stream>>>(Q, KV, deg, colb, h1, N);

    dim3 gq(nqx, 3);
    // conv2: IN=128, input = h1 * dm_mask (mask fused into staging; x2 gathers unmasked h1)
    qkv_kernel<<<gq, 256, 0, stream>>>(h1, dm, WT2, c2bq, c2bk, c2bv, Q, KV, N, 128);
    attn_kernel<<<(N + 3) / 4, 256, 0, stream>>>(Q, KV, deg, colb, h2, N);

    head_kernel<<<(B * 5 + 255) / 256, 256, 0, stream>>>(h0, h1, h2, gi, ow, ob, out, B);
}